// Round 11
// baseline (6122.455 us; speedup 1.0000x reference)
//
#include <hip/hip_runtime.h>
#include <math.h>

#define B_SZ 4096
#define T_SZ 80
#define V_SZ 80
#define E_SZ 8
#define H_SZ 256
#define G4   1024   // 4*H
#define RB   32     // rows per persistent block
#define NBLK (B_SZ / RB)   // 128 blocks

typedef __attribute__((ext_vector_type(8))) short short8;
typedef __attribute__((ext_vector_type(4))) float f32x4;

__device__ __forceinline__ float sigm(float x) {
    return 1.f / (1.f + __expf(-x));
}
__device__ __forceinline__ float tanhfast(float x) {
    x = fminf(fmaxf(x, -15.f), 15.f);
    float t = __expf(-2.f * x);
    return (1.f - t) / (1.f + t);
}
__device__ __forceinline__ ushort f2bf(float f) {   // RNE f32->bf16
    unsigned u = __float_as_uint(f);
    u = (u + 0x7fffu + ((u >> 16) & 1u)) >> 16;
    return (ushort)u;
}
__device__ __forceinline__ f32x4 mfma16(short8 a, short8 b, f32x4 c) {
    return __builtin_amdgcn_mfma_f32_16x16x32_bf16(a, b, c, 0, 0, 0);
}

// G1[v][col] = b1[col] + sum_e emb[v][e] * W1[e][col]
__global__ __launch_bounds__(256) void g1_kernel(const float* __restrict__ emb,
                                                 const float* __restrict__ W1,
                                                 const float* __restrict__ b1,
                                                 float* __restrict__ G1) {
    int idx = blockIdx.x * 256 + threadIdx.x;
    if (idx >= V_SZ * G4) return;
    int v = idx >> 10, col = idx & 1023;
    float g = b1[col];
#pragma unroll
    for (int e = 0; e < E_SZ; e++)
        g += emb[v * E_SZ + e] * W1[e * G4 + col];
    G1[idx] = g;
}

// Fragment-ordered weights for the row-local kernel.
// flat idx = ((w*KT + kt)*8 + cf)*512 + l*8 + j
//   k   = k0 + kt*32 + (l>>4)*8 + j
//   col = (cf>>1)*256 + w*32 + (cf&1)*16 + (l&15)
__global__ __launch_bounds__(256) void wtransf2(const float* __restrict__ src, int k0,
                                                int KTmask, int KTsh,
                                                ushort* __restrict__ out) {
    int idx = blockIdx.x * 256 + threadIdx.x;
    int j  = idx & 7;
    int l  = (idx >> 3) & 63;
    int cf = (idx >> 9) & 7;
    int kt = (idx >> 12) & KTmask;
    int w  = idx >> (12 + KTsh);
    int k  = k0 + kt * 32 + (l >> 4) * 8 + j;
    int col = (cf >> 1) * 256 + w * 32 + (cf & 1) * 16 + (l & 15);
    out[idx] = f2bf(src[(size_t)k * G4 + col]);
}

// WdT[v][h] = bf16(Wd[h*V + v])
__global__ __launch_bounds__(256) void wdtrans(const float* __restrict__ src,
                                               ushort* __restrict__ out) {
    int idx = blockIdx.x * 256 + threadIdx.x;
    if (idx >= V_SZ * H_SZ) return;
    int v = idx >> 8, h = idx & 255;
    out[idx] = f2bf(src[h * V_SZ + v]);
}

// ---------------------------------------------------------------------------
// Persistent row-local 2-layer LSTM (R10 structure) + per-timestep lockstep
// soft barrier. The barrier is a PERFORMANCE rate-limiter only: h1/h2/c are
// block-local (LDS/registers), so correctness never depends on it; the spin
// has a bail-out. 1 block/CU (88KB LDS) -> all 128 blocks co-resident.
// ---------------------------------------------------------------------------
__global__ __launch_bounds__(512) void lstm_rowlocal(
    const int*   __restrict__ feat,
    const float* __restrict__ G1,
    const float* __restrict__ b2,
    const ushort* __restrict__ W1f,
    const ushort* __restrict__ W2f,
    ushort* __restrict__ h2g,
    int* __restrict__ cnt,
    int padsel) {

    __shared__ __align__(16) ushort h1s[2][8192];   // 2 x 16 KB
    __shared__ __align__(16) ushort h2s[2][8192];   // 2 x 16 KB
    __shared__ ushort pad[12288];                   // 24 KB -> 88 KB total: 1 block/CU

    const int tid = threadIdx.x;
    const int w = tid >> 6, l = tid & 63;
    const int l15 = l & 15, l4 = l >> 4;
    const int m0 = blockIdx.x * RB;

    if (padsel) {                       // never true at runtime; keeps pad live
        pad[tid] = (ushort)tid;
        h2g[tid] = pad[tid ^ 1];
    }

    float bb[8];
#pragma unroll
    for (int cf = 0; cf < 8; cf++)
        bb[cf] = b2[(cf >> 1) * 256 + w * 32 + (cf & 1) * 16 + l15];

    float c1r[16], c2r[16];             // cell idx = (rt*4+r)*2 + hh
#pragma unroll
    for (int i = 0; i < 16; i++) { c1r[i] = 0.f; c2r[i] = 0.f; }

    const ushort* w1p = W1f + (size_t)(w * 8) * 8 * 512 + l * 8;
    const ushort* w2p = W2f + (size_t)(w * 16) * 8 * 512 + l * 8;

    const int hwrB = (l15 >> 3);
    const f32x4 zero4 = {0.f, 0.f, 0.f, 0.f};

#pragma unroll 1
    for (int t = 0; t < T_SZ; t++) {
        // ================= phase A: layer 1 (K = 256, h1(t-1)) =================
        f32x4 acc[2][8];
#pragma unroll
        for (int rt = 0; rt < 2; rt++)
#pragma unroll
            for (int cf = 0; cf < 8; cf++) acc[rt][cf] = zero4;

        if (t > 0) {
            const ushort* ab = h1s[(t + 1) & 1];    // h1(t-1)
            short8 wf[2][8];
#pragma unroll
            for (int cf = 0; cf < 8; cf++)
                wf[0][cf] = *(const short8*)(w1p + (size_t)cf * 512);
#pragma unroll
            for (int kt = 0; kt < 8; kt++) {
                if (kt < 7) {
#pragma unroll
                    for (int cf = 0; cf < 8; cf++)
                        wf[(kt + 1) & 1][cf] =
                            *(const short8*)(w1p + ((size_t)(kt + 1) * 8 + cf) * 512);
                }
                short8 a0 = *(const short8*)(ab + (0 * 8 + kt) * 512 + l * 8);
                short8 a1 = *(const short8*)(ab + (1 * 8 + kt) * 512 + l * 8);
                __builtin_amdgcn_s_setprio(1);
#pragma unroll
                for (int cf = 0; cf < 8; cf++) {
                    acc[0][cf] = mfma16(a0, wf[kt & 1][cf], acc[0][cf]);
                    acc[1][cf] = mfma16(a1, wf[kt & 1][cf], acc[1][cf]);
                }
                __builtin_amdgcn_s_setprio(0);
            }
        }

        {   // epilogue L1 -> h1s[t&1]
            ushort* ho = h1s[t & 1];
#pragma unroll
            for (int rt = 0; rt < 2; rt++) {
#pragma unroll
                for (int r = 0; r < 4; r++) {
                    const int row = rt * 16 + l4 * 4 + r;
                    const int fr = feat[(size_t)(m0 + row) * T_SZ + t];
                    const float* gr = G1 + (size_t)fr * G4;
#pragma unroll
                    for (int hh = 0; hh < 2; hh++) {
                        const int hc = w * 32 + hh * 16 + l15;
                        float gi = acc[rt][0 + hh][r] + gr[hc];
                        float gj = acc[rt][2 + hh][r] + gr[256 + hc];
                        float gf = acc[rt][4 + hh][r] + gr[512 + hc];
                        float go = acc[rt][6 + hh][r] + gr[768 + hc];
                        const int ci = (rt * 4 + r) * 2 + hh;
                        float cp = t ? c1r[ci] : 0.f;
                        float cn = cp * sigm(gf + 1.f) + sigm(gi) * tanhfast(gj);
                        float hn = tanhfast(cn) * sigm(go);
                        c1r[ci] = cn;
                        ho[(rt * 8 + w) * 512 +
                           ((row & 15) + (hh * 2 + hwrB) * 16) * 8 + (l15 & 7)] = f2bf(hn);
                    }
                }
            }
        }
        __syncthreads();

        // ============ phase B: layer 2 (K = 512: h1(t) ++ h2(t-1)) ============
#pragma unroll
        for (int rt = 0; rt < 2; rt++)
#pragma unroll
            for (int cf = 0; cf < 8; cf++) acc[rt][cf] = zero4;

        {
            const ushort* a1b = h1s[t & 1];         // h1(t):   k 0..255
            const ushort* a2b = h2s[(t + 1) & 1];   // h2(t-1): k 256..511
            short8 wf[2][8];
#pragma unroll
            for (int cf = 0; cf < 8; cf++)
                wf[0][cf] = *(const short8*)(w2p + (size_t)cf * 512);
#pragma unroll
            for (int kt = 0; kt < 8; kt++) {
#pragma unroll
                for (int cf = 0; cf < 8; cf++)
                    wf[(kt + 1) & 1][cf] =
                        *(const short8*)(w2p + ((size_t)(kt + 1) * 8 + cf) * 512);
                short8 a0 = *(const short8*)(a1b + (0 * 8 + kt) * 512 + l * 8);
                short8 a1 = *(const short8*)(a1b + (1 * 8 + kt) * 512 + l * 8);
                __builtin_amdgcn_s_setprio(1);
#pragma unroll
                for (int cf = 0; cf < 8; cf++) {
                    acc[0][cf] = mfma16(a0, wf[kt & 1][cf], acc[0][cf]);
                    acc[1][cf] = mfma16(a1, wf[kt & 1][cf], acc[1][cf]);
                }
                __builtin_amdgcn_s_setprio(0);
            }
            if (t > 0) {
#pragma unroll
                for (int kt = 8; kt < 16; kt++) {
                    if (kt < 15) {
#pragma unroll
                        for (int cf = 0; cf < 8; cf++)
                            wf[(kt + 1) & 1][cf] =
                                *(const short8*)(w2p + ((size_t)(kt + 1) * 8 + cf) * 512);
                    }
                    short8 a0 = *(const short8*)(a2b + (0 * 8 + kt - 8) * 512 + l * 8);
                    short8 a1 = *(const short8*)(a2b + (1 * 8 + kt - 8) * 512 + l * 8);
                    __builtin_amdgcn_s_setprio(1);
#pragma unroll
                    for (int cf = 0; cf < 8; cf++) {
                        acc[0][cf] = mfma16(a0, wf[kt & 1][cf], acc[0][cf]);
                        acc[1][cf] = mfma16(a1, wf[kt & 1][cf], acc[1][cf]);
                    }
                    __builtin_amdgcn_s_setprio(0);
                }
            }
        }

        {   // epilogue L2 -> h2s[t&1]; at t=79 also emit h2 row-major to global
            ushort* ho = h2s[t & 1];
#pragma unroll
            for (int rt = 0; rt < 2; rt++) {
#pragma unroll
                for (int r = 0; r < 4; r++) {
                    const int row = rt * 16 + l4 * 4 + r;
#pragma unroll
                    for (int hh = 0; hh < 2; hh++) {
                        const int hc = w * 32 + hh * 16 + l15;
                        float gi = acc[rt][0 + hh][r] + bb[0 + hh];
                        float gj = acc[rt][2 + hh][r] + bb[2 + hh];
                        float gf = acc[rt][4 + hh][r] + bb[4 + hh];
                        float go = acc[rt][6 + hh][r] + bb[6 + hh];
                        const int ci = (rt * 4 + r) * 2 + hh;
                        float cp = t ? c2r[ci] : 0.f;
                        float cn = cp * sigm(gf + 1.f) + sigm(gi) * tanhfast(gj);
                        float hn = tanhfast(cn) * sigm(go);
                        c2r[ci] = cn;
                        ushort hb = f2bf(hn);
                        ho[(rt * 8 + w) * 512 +
                           ((row & 15) + (hh * 2 + hwrB) * 16) * 8 + (l15 & 7)] = hb;
                        if (t == T_SZ - 1)
                            h2g[(size_t)(m0 + row) * H_SZ + hc] = hb;
                    }
                }
            }
        }
        __syncthreads();

        // ---- lockstep soft barrier (performance only; correctness-independent)
        if (t < T_SZ - 1) {
            if (tid == 0) {
                __hip_atomic_fetch_add(&cnt[t], 1, __ATOMIC_RELAXED,
                                       __HIP_MEMORY_SCOPE_AGENT);
                int n = 0;
                while (__hip_atomic_load(&cnt[t], __ATOMIC_RELAXED,
                                         __HIP_MEMORY_SCOPE_AGENT) < NBLK) {
                    __builtin_amdgcn_s_sleep(4);
                    if (++n > (1 << 16)) break;   // harmless bail-out
                }
            }
            __syncthreads();
        }
    }
}

// dense+loss via MFMA: wave computes 16 rows x 80 v-cols; shfl softmax.
__global__ __launch_bounds__(256) void dense_loss(const ushort* __restrict__ h2,
                                                  const ushort* __restrict__ WdT,
                                                  const float* __restrict__ bd,
                                                  const int* __restrict__ labels,
                                                  float* __restrict__ out) {
    const int tid = threadIdx.x;
    const int w = tid >> 6, l = tid & 63;
    const int l15 = l & 15, l4 = l >> 4;
    const int m0 = blockIdx.x * 64 + w * 16;

    f32x4 acc[5];
    const f32x4 zero4 = {0.f, 0.f, 0.f, 0.f};
#pragma unroll
    for (int cf = 0; cf < 5; cf++) acc[cf] = zero4;

    for (int kt = 0; kt < 256; kt += 32) {
        short8 a = *(const short8*)(h2 + (size_t)(m0 + l15) * H_SZ + l4 * 8 + kt);
#pragma unroll
        for (int cf = 0; cf < 5; cf++) {
            short8 b = *(const short8*)(WdT + (size_t)(cf * 16 + l15) * H_SZ + l4 * 8 + kt);
            acc[cf] = __builtin_amdgcn_mfma_f32_16x16x32_bf16(a, b, acc[cf], 0, 0, 0);
        }
    }
#pragma unroll
    for (int cf = 0; cf < 5; cf++) {
        float bv = bd[cf * 16 + l15];
#pragma unroll
        for (int r = 0; r < 4; r++) acc[cf][r] += bv;
    }

#pragma unroll
    for (int r = 0; r < 4; r++) {
        const int row = m0 + l4 * 4 + r;
        float mx = acc[0][r];
#pragma unroll
        for (int cf = 1; cf < 5; cf++) mx = fmaxf(mx, acc[cf][r]);
#pragma unroll
        for (int msk = 1; msk < 16; msk <<= 1)
            mx = fmaxf(mx, __shfl_xor(mx, msk, 64));
        float s = 0.f;
#pragma unroll
        for (int cf = 0; cf < 5; cf++) s += __expf(acc[cf][r] - mx);
#pragma unroll
        for (int msk = 1; msk < 16; msk <<= 1)
            s += __shfl_xor(s, msk, 64);
        const int lab = labels[row];
        float pl = 0.f;
#pragma unroll
        for (int cf = 0; cf < 5; cf++)
            pl += (cf * 16 + l15 == lab) ? acc[cf][r] : 0.f;
#pragma unroll
        for (int msk = 1; msk < 16; msk <<= 1)
            pl += __shfl_xor(pl, msk, 64);
        if (l15 == 0)
            atomicAdd(out, (logf(s) + mx - pl) * (1.0f / B_SZ));
    }
}

extern "C" void kernel_launch(void* const* d_in, const int* in_sizes, int n_in,
                              void* d_out, int out_size, void* d_ws, size_t ws_size,
                              hipStream_t stream) {
    const int*   features = (const int*)d_in[0];
    const int*   labels   = (const int*)d_in[1];
    const float* emb      = (const float*)d_in[2];
    const float* W1       = (const float*)d_in[3];
    const float* b1       = (const float*)d_in[4];
    const float* W2       = (const float*)d_in[5];
    const float* b2       = (const float*)d_in[6];
    const float* Wd       = (const float*)d_in[7];
    const float* bd       = (const float*)d_in[8];
    float* out = (float*)d_out;

    char* base = (char*)d_ws;
    float*  G1v = (float*)base;      base += (size_t)V_SZ * G4 * 4;            // 320 KB
    ushort* W1f = (ushort*)base;     base += (size_t)8 * 8 * 8 * 512 * 2;      // 512 KB
    ushort* W2f = (ushort*)base;     base += (size_t)8 * 16 * 8 * 512 * 2;     // 1 MB
    ushort* WdT = (ushort*)base;     base += (size_t)V_SZ * H_SZ * 2;          // 40 KB
    ushort* h2g = (ushort*)base;     base += (size_t)B_SZ * H_SZ * 2;          // 2 MB
    int*    cnt = (int*)base;        base += (size_t)T_SZ * 4;                 // 320 B

    (void)hipMemsetAsync(d_out, 0, sizeof(float), stream);
    (void)hipMemsetAsync(cnt, 0, (size_t)T_SZ * 4, stream);

    g1_kernel<<<(V_SZ * G4 + 255) / 256, 256, 0, stream>>>(emb, W1, b1, G1v);
    wtransf2<<<(8 * 8 * 8 * 512) / 256, 256, 0, stream>>>(W1, E_SZ, 7, 3, W1f);
    wtransf2<<<(8 * 16 * 8 * 512) / 256, 256, 0, stream>>>(W2, 0, 15, 4, W2f);
    wdtrans<<<(V_SZ * H_SZ + 255) / 256, 256, 0, stream>>>(Wd, WdT);

    lstm_rowlocal<<<NBLK, 512, 0, stream>>>(features, G1v, b2, W1f, W2f, h2g, cnt, 0);

    dense_loss<<<B_SZ / 64, 256, 0, stream>>>(h2g, WdT, bd, labels, out);
}

// Round 12
// 2996.806 us; speedup vs baseline: 2.0430x; 2.0430x over previous
//
#include <hip/hip_runtime.h>
#include <math.h>

#define B_SZ 4096
#define T_SZ 80
#define V_SZ 80
#define E_SZ 8
#define H_SZ 256
#define G4   1024   // 4*H

typedef __attribute__((ext_vector_type(8))) short short8;
typedef __attribute__((ext_vector_type(4))) float f32x4;

typedef __attribute__((address_space(1))) const unsigned gu32;
typedef __attribute__((address_space(3))) unsigned su32;

__device__ __forceinline__ void glds16(const ushort* g, ushort* l) {
    __builtin_amdgcn_global_load_lds((gu32*)g, (su32*)l, 16, 0, 0);
}

__device__ __forceinline__ float sigm(float x) {
    return 1.f / (1.f + __expf(-x));
}
__device__ __forceinline__ float tanhfast(float x) {
    x = fminf(fmaxf(x, -15.f), 15.f);
    float t = __expf(-2.f * x);
    return (1.f - t) / (1.f + t);
}
__device__ __forceinline__ ushort f2bf(float f) {   // RNE f32->bf16
    unsigned u = __float_as_uint(f);
    u = (u + 0x7fffu + ((u >> 16) & 1u)) >> 16;
    return (ushort)u;
}
__device__ __forceinline__ f32x4 mfma16(short8 a, short8 b, f32x4 c) {
    return __builtin_amdgcn_mfma_f32_16x16x32_bf16(a, b, c, 0, 0, 0);
}

// G1[v][col] = b1[col] + sum_e emb[v][e] * W1[e][col]
__global__ __launch_bounds__(256) void g1_kernel(const float* __restrict__ emb,
                                                 const float* __restrict__ W1,
                                                 const float* __restrict__ b1,
                                                 float* __restrict__ G1) {
    int idx = blockIdx.x * 256 + threadIdx.x;
    if (idx >= V_SZ * G4) return;
    int v = idx >> 10, col = idx & 1023;
    float g = b1[col];
#pragma unroll
    for (int e = 0; e < E_SZ; e++)
        g += emb[v * E_SZ + e] * W1[e * G4 + col];
    G1[idx] = g;
}

// Fragment-ordered weight transpose (same layout as R9).
// out ushort idx = ((hb*KT + kt32)*8 + cf)*512 + l*8 + j
//   k   = k0 + kt32*32 + (l>>4)*8 + j
//   col = (cf>>1)*256 + hb*32 + (cf&1)*16 + (l&15)
__global__ __launch_bounds__(256) void wtransf(const float* __restrict__ src, int k0,
                                               int KTmask, int KTsh,
                                               ushort* __restrict__ out) {
    int idx = blockIdx.x * 256 + threadIdx.x;
    int j = idx & 7;
    int c = (idx >> 3) & 511;
    int ktile = (idx >> 12) & KTmask;
    int hb = idx >> (12 + KTsh);
    int cf = c >> 6;
    int k = k0 + ktile * 32 + ((c >> 4) & 3) * 8 + j;
    // NOTE: (c>>4)&3 here equals (l>>4) since c = cf*64 + l
    int ncol = (cf >> 1) * 256 + hb * 32 + (cf & 1) * 16 + (c & 15);
    out[idx] = f2bf(src[(size_t)k * G4 + ncol]);
}

// WdT[v][h] = bf16(Wd[h*V + v])
__global__ __launch_bounds__(256) void wdtrans(const float* __restrict__ src,
                                               ushort* __restrict__ out) {
    int idx = blockIdx.x * 256 + threadIdx.x;
    if (idx >= V_SZ * H_SZ) return;
    int v = idx >> 8, h = idx & 255;
    out[idx] = f2bf(src[h * V_SZ + v]);
}

// Fused step: blockIdx.z==0 -> layer1(t); z==1 -> layer2(t-1)  (skewed pipeline).
// Grid (m-group, h-block, z) for XCD locality of A-slices.
// Block = 128 rows x (4 gates x 32 hcols); 4 waves; BK=64 double-buffer:
// half the barrier drains of the BK=32 version. Fragment-linear LDS (0 conflicts).
__global__ __launch_bounds__(256) void lstm_fused(
    const ushort* __restrict__ A1h, int Kend1,
    const int*   __restrict__ feat,   // features + t
    const float* __restrict__ G1,
    float* __restrict__ c1, ushort* __restrict__ h1out,
    const ushort* __restrict__ A2x, const ushort* __restrict__ A2h, int Kend2,
    const float* __restrict__ b2,
    float* __restrict__ c2, ushort* __restrict__ h2out,
    const ushort* __restrict__ W1f, const ushort* __restrict__ W2f) {

    const int z = blockIdx.z;
    const int Kend = z ? Kend2 : Kend1;
    if (Kend < 0) return;
    const int KT = z ? 16 : 8;                 // 32-k tiles in W layout
    const ushort* __restrict__ Wf = z ? W2f : W1f;

    __shared__ __align__(16) ushort As[2][8192];   // 1024 chunks x 16B
    __shared__ __align__(16) ushort Ws[2][8192];

    const int tid = threadIdx.x;
    const int w = tid >> 6, l = tid & 63;
    const int l15 = l & 15, l4 = l >> 4;
    const int m0 = blockIdx.x * 128;
    const int hb = blockIdx.y;
    const int h0 = hb * 32;

    // ---- staging precompute: thread stages chunks c = tid + i*256, i=0..3
    // A chunk c: wq=c>>8, f=(c>>6)&3 (rt=f>>1, ks=f&1), lp=c&63
    //   row = wq*32 + rt*16 + (lp&15);  kk = ks*32 + (lp>>4)*8
    int arow[4], akk[4];
    size_t woff[4];
#pragma unroll
    for (int i = 0; i < 4; i++) {
        const int c = tid + i * 256;
        const int wq = c >> 8, f = (c >> 6) & 3, lp = c & 63;
        arow[i] = wq * 32 + (f >> 1) * 16 + (lp & 15);
        akk[i]  = (f & 1) * 32 + (lp >> 4) * 8;
        // W chunk c: ks=c>>9, cf=(c>>6)&7, lp=c&63 -> frag (kt32=2*kt64+ks, cf)
        const int ks = c >> 9, cf = (c >> 6) & 7;
        woff[i] = ((size_t)ks * 8 + cf) * 512 + lp * 8;
    }
    const size_t wbase = (size_t)hb * KT * 8 * 512;   // ushorts

    // fragment read offsets (ushorts)
    // A frag (rt,ks) for wave w: chunk (w*4 + rt*2 + ks)*64 + l
    // W frag (cf,ks): chunk ks*512 + cf*64 + l
    const int abase = (w * 4) * 64 + l;

    f32x4 acc[2][8];
    const f32x4 zero4 = {0.f, 0.f, 0.f, 0.f};
#pragma unroll
    for (int rt = 0; rt < 2; rt++)
#pragma unroll
        for (int cf = 0; cf < 8; cf++) acc[rt][cf] = zero4;

    auto stage = [&](int buf, int kt64) {
        const int klbase = kt64 * 64;
#pragma unroll
        for (int i = 0; i < 4; i++) {
            const int kk = klbase + akk[i];
            const ushort* Asrc; int kl;
            if (!z || kk < 256) { Asrc = z ? A2x : A1h; kl = kk; }
            else                { Asrc = A2h; kl = kk - 256; }
            glds16(Asrc + (size_t)(m0 + arow[i]) * H_SZ + kl,
                   As[buf] + (size_t)(tid + i * 256) * 8);
        }
        const ushort* ws = Wf + wbase + (size_t)kt64 * 8192;
#pragma unroll
        for (int i = 0; i < 4; i++)
            glds16(ws + woff[i], Ws[buf] + (size_t)(tid + i * 256) * 8);
    };

    if (Kend > 0) {
        const int NT = Kend >> 6;              // 64-k tiles
        stage(0, 0);
        __syncthreads();
        int cur = 0;
        for (int kt64 = 0; kt64 < NT; kt64++) {
            // ks = 0 half
            short8 a00 = *(const short8*)(As[cur] + (abase + 0 * 64) * 8);   // rt0 ks0
            short8 a10 = *(const short8*)(As[cur] + (abase + 2 * 64) * 8);   // rt1 ks0
            short8 b0[8];
#pragma unroll
            for (int cf = 0; cf < 8; cf++)
                b0[cf] = *(const short8*)(Ws[cur] + (cf * 64 + l) * 8);

            if (kt64 + 1 < NT) stage(cur ^ 1, kt64 + 1);

            __builtin_amdgcn_s_setprio(1);
#pragma unroll
            for (int cf = 0; cf < 8; cf++) {
                acc[0][cf] = mfma16(a00, b0[cf], acc[0][cf]);
                acc[1][cf] = mfma16(a10, b0[cf], acc[1][cf]);
            }
            __builtin_amdgcn_s_setprio(0);

            // ks = 1 half
            short8 a01 = *(const short8*)(As[cur] + (abase + 1 * 64) * 8);   // rt0 ks1
            short8 a11 = *(const short8*)(As[cur] + (abase + 3 * 64) * 8);   // rt1 ks1
            short8 b1[8];
#pragma unroll
            for (int cf = 0; cf < 8; cf++)
                b1[cf] = *(const short8*)(Ws[cur] + (512 * 8) + (cf * 64 + l) * 8);

            __builtin_amdgcn_s_setprio(1);
#pragma unroll
            for (int cf = 0; cf < 8; cf++) {
                acc[0][cf] = mfma16(a01, b1[cf], acc[0][cf]);
                acc[1][cf] = mfma16(a11, b1[cf], acc[1][cf]);
            }
            __builtin_amdgcn_s_setprio(0);

            __syncthreads();
            cur ^= 1;
        }
    }

    // fused LSTM cell epilogue. D layout: row=(l>>4)*4+r, col=l&15.
    float* __restrict__ cbuf = z ? c2 : c1;
    ushort* __restrict__ hout = z ? h2out : h1out;
    const bool cz = z ? (Kend == 256) : (Kend == 0);

#pragma unroll
    for (int rt = 0; rt < 2; rt++) {
#pragma unroll
        for (int r = 0; r < 4; r++) {
            const int grow = m0 + w * 32 + rt * 16 + l4 * 4 + r;
            const float* gb = z ? b2 : (G1 + (size_t)feat[(size_t)grow * T_SZ] * G4);
#pragma unroll
            for (int h16 = 0; h16 < 2; h16++) {
                const int hcol = h0 + h16 * 16 + l15;
                float gi = acc[rt][0 + h16][r] + gb[hcol];
                float gj = acc[rt][2 + h16][r] + gb[256 + hcol];
                float gf = acc[rt][4 + h16][r] + gb[512 + hcol];
                float go = acc[rt][6 + h16][r] + gb[768 + hcol];
                const size_t ci = (size_t)grow * H_SZ + hcol;
                float cp = cz ? 0.f : cbuf[ci];
                float cn = cp * sigm(gf + 1.f) + sigm(gi) * tanhfast(gj);
                float hn = tanhfast(cn) * sigm(go);
                cbuf[ci] = cn;
                hout[ci] = f2bf(hn);
            }
        }
    }
}

// dense+loss via MFMA: wave computes 16 rows x 80 v-cols; shfl softmax.
__global__ __launch_bounds__(256) void dense_loss(const ushort* __restrict__ h2,
                                                  const ushort* __restrict__ WdT,
                                                  const float* __restrict__ bd,
                                                  const int* __restrict__ labels,
                                                  float* __restrict__ out) {
    const int tid = threadIdx.x;
    const int w = tid >> 6, l = tid & 63;
    const int l15 = l & 15, l4 = l >> 4;
    const int m0 = blockIdx.x * 64 + w * 16;

    f32x4 acc[5];
    const f32x4 zero4 = {0.f, 0.f, 0.f, 0.f};
#pragma unroll
    for (int cf = 0; cf < 5; cf++) acc[cf] = zero4;

    for (int kt = 0; kt < 256; kt += 32) {
        short8 a = *(const short8*)(h2 + (size_t)(m0 + l15) * H_SZ + l4 * 8 + kt);
#pragma unroll
        for (int cf = 0; cf < 5; cf++) {
            short8 b = *(const short8*)(WdT + (size_t)(cf * 16 + l15) * H_SZ + l4 * 8 + kt);
            acc[cf] = __builtin_amdgcn_mfma_f32_16x16x32_bf16(a, b, acc[cf], 0, 0, 0);
        }
    }
#pragma unroll
    for (int cf = 0; cf < 5; cf++) {
        float bv = bd[cf * 16 + l15];
#pragma unroll
        for (int r = 0; r < 4; r++) acc[cf][r] += bv;
    }

#pragma unroll
    for (int r = 0; r < 4; r++) {
        const int row = m0 + l4 * 4 + r;
        float mx = acc[0][r];
#pragma unroll
        for (int cf = 1; cf < 5; cf++) mx = fmaxf(mx, acc[cf][r]);
#pragma unroll
        for (int msk = 1; msk < 16; msk <<= 1)
            mx = fmaxf(mx, __shfl_xor(mx, msk, 64));
        float s = 0.f;
#pragma unroll
        for (int cf = 0; cf < 5; cf++) s += __expf(acc[cf][r] - mx);
#pragma unroll
        for (int msk = 1; msk < 16; msk <<= 1)
            s += __shfl_xor(s, msk, 64);
        const int lab = labels[row];
        float pl = 0.f;
#pragma unroll
        for (int cf = 0; cf < 5; cf++)
            pl += (cf * 16 + l15 == lab) ? acc[cf][r] : 0.f;
#pragma unroll
        for (int msk = 1; msk < 16; msk <<= 1)
            pl += __shfl_xor(pl, msk, 64);
        if (l15 == 0)
            atomicAdd(out, (logf(s) + mx - pl) * (1.0f / B_SZ));
    }
}

extern "C" void kernel_launch(void* const* d_in, const int* in_sizes, int n_in,
                              void* d_out, int out_size, void* d_ws, size_t ws_size,
                              hipStream_t stream) {
    const int*   features = (const int*)d_in[0];
    const int*   labels   = (const int*)d_in[1];
    const float* emb      = (const float*)d_in[2];
    const float* W1       = (const float*)d_in[3];
    const float* b1       = (const float*)d_in[4];
    const float* W2       = (const float*)d_in[5];
    const float* b2       = (const float*)d_in[6];
    const float* Wd       = (const float*)d_in[7];
    const float* bd       = (const float*)d_in[8];
    float* out = (float*)d_out;

    char* base = (char*)d_ws;
    float*  G1v = (float*)base;      base += (size_t)V_SZ * G4 * 4;            // 320 KB
    float*  c1  = (float*)base;      base += (size_t)B_SZ * H_SZ * 4;          // 4 MB
    float*  c2  = (float*)base;      base += (size_t)B_SZ * H_SZ * 4;          // 4 MB
    ushort* h1b[2]; ushort* h2b[2];
    h1b[0] = (ushort*)base;          base += (size_t)B_SZ * H_SZ * 2;
    h1b[1] = (ushort*)base;          base += (size_t)B_SZ * H_SZ * 2;
    h2b[0] = (ushort*)base;          base += (size_t)B_SZ * H_SZ * 2;
    h2b[1] = (ushort*)base;          base += (size_t)B_SZ * H_SZ * 2;
    ushort* W1f = (ushort*)base;     base += (size_t)8 * 8 * 512 * 8 * 2;      // 512 KB
    ushort* W2f = (ushort*)base;     base += (size_t)8 * 16 * 512 * 8 * 2;     // 1 MB
    ushort* WdT = (ushort*)base;     base += (size_t)V_SZ * H_SZ * 2;          // 40 KB

    (void)hipMemsetAsync(d_out, 0, sizeof(float), stream);
    g1_kernel<<<(V_SZ * G4 + 255) / 256, 256, 0, stream>>>(emb, W1, b1, G1v);
    wtransf<<<(8 * 8 * 512 * 8) / 256, 256, 0, stream>>>(W1, E_SZ, 7, 3, W1f);
    wtransf<<<(8 * 16 * 512 * 8) / 256, 256, 0, stream>>>(W2, 0, 15, 4, W2f);
    wdtrans<<<(V_SZ * H_SZ + 255) / 256, 256, 0, stream>>>(Wd, WdT);

    dim3 grid(B_SZ / 128, H_SZ / 32, 2), blk(256);
    for (int t = 0; t <= T_SZ; t++) {
        const int Kend1 = (t < T_SZ) ? (t ? 256 : 0) : -1;
        const int Kend2 = (t >= 1) ? ((t >= 2) ? 512 : 256) : -1;
        lstm_fused<<<grid, blk, 0, stream>>>(
            (t && t < T_SZ) ? h1b[(t - 1) & 1] : nullptr, Kend1,
            features + t, G1v, c1, h1b[t & 1],
            (t >= 1) ? h1b[(t - 1) & 1] : nullptr,
            (t >= 2) ? h2b[(t - 2) & 1] : nullptr, Kend2,
            b2, c2, (t >= 1) ? h2b[(t - 1) & 1] : nullptr,
            W1f, W2f);
    }
    dense_loss<<<B_SZ / 64, 256, 0, stream>>>(h2b[(T_SZ - 1) & 1], WdT, bd, labels, out);
}

// Round 13
// 1609.922 us; speedup vs baseline: 3.8030x; 1.8615x over previous
//
#include <hip/hip_runtime.h>
#include <math.h>

#define B_SZ 4096
#define T_SZ 80
#define V_SZ 80
#define E_SZ 8
#define H_SZ 256
#define G4   1024   // 4*H

typedef __attribute__((ext_vector_type(8))) short short8;
typedef __attribute__((ext_vector_type(4))) float f32x4;

typedef __attribute__((address_space(1))) const unsigned gu32;
typedef __attribute__((address_space(3))) unsigned su32;

__device__ __forceinline__ void glds16(const ushort* g, ushort* l) {
    __builtin_amdgcn_global_load_lds((gu32*)g, (su32*)l, 16, 0, 0);
}

__device__ __forceinline__ float sigm(float x) {
    return 1.f / (1.f + __expf(-x));
}
__device__ __forceinline__ float tanhfast(float x) {
    x = fminf(fmaxf(x, -15.f), 15.f);
    float t = __expf(-2.f * x);
    return (1.f - t) / (1.f + t);
}
__device__ __forceinline__ ushort f2bf(float f) {   // RNE f32->bf16
    unsigned u = __float_as_uint(f);
    u = (u + 0x7fffu + ((u >> 16) & 1u)) >> 16;
    return (ushort)u;
}
__device__ __forceinline__ float bf2f(ushort s) {
    return __uint_as_float(((unsigned)s) << 16);
}

// G1[v][col] = b1[col] + sum_e emb[v][e] * W1[e][col]
__global__ __launch_bounds__(256) void g1_kernel(const float* __restrict__ emb,
                                                 const float* __restrict__ W1,
                                                 const float* __restrict__ b1,
                                                 float* __restrict__ G1) {
    int idx = blockIdx.x * 256 + threadIdx.x;
    if (idx >= V_SZ * G4) return;
    int v = idx >> 10, col = idx & 1023;
    float g = b1[col];
#pragma unroll
    for (int e = 0; e < E_SZ; e++)
        g += emb[v * E_SZ + e] * W1[e * G4 + col];
    G1[idx] = g;
}

// Fragment-ordered weight transpose.
// out[((hb*KT + ktile)*512 + c)*8 + j] = bf16(src[(k0 + ktile*32 + kq*8 + j)*1024 + ncol])
//   c = cf*64 + l;  kq=(c>>4)&3; ncol = (cf>>1)*256 + hb*32 + (cf&1)*16 + (c&15)
__global__ __launch_bounds__(256) void wtransf(const float* __restrict__ src, int k0,
                                               int KTmask, int KTsh,
                                               ushort* __restrict__ out) {
    int idx = blockIdx.x * 256 + threadIdx.x;
    int j = idx & 7;
    int c = (idx >> 3) & 511;
    int ktile = (idx >> 12) & KTmask;
    int hb = idx >> (12 + KTsh);
    int cf = c >> 6;
    int k = k0 + ktile * 32 + ((c >> 4) & 3) * 8 + j;
    int ncol = (cf >> 1) * 256 + hb * 32 + (cf & 1) * 16 + (c & 15);
    out[idx] = f2bf(src[(size_t)k * G4 + ncol]);
}

// WdT[v][h] = bf16(Wd[h*V + v])
__global__ __launch_bounds__(256) void wdtrans(const float* __restrict__ src,
                                               ushort* __restrict__ out) {
    int idx = blockIdx.x * 256 + threadIdx.x;
    if (idx >= V_SZ * H_SZ) return;
    int v = idx >> 8, h = idx & 255;
    out[idx] = f2bf(src[h * V_SZ + v]);
}

// Fused step: blockIdx.z==0 -> layer1(t); z==1 -> layer2(t-1)  (skewed pipeline).
// Grid (m-group, h-block, z) for XCD locality of A-slices.
// Block = 128 rows x (4 gates x 32 hcols); 4 waves, wave w owns rows w*32..w*32+31.
// LDS fragment-linear (0 conflicts); BK=32 double-buffered glds staging.
// Cell state c kept in GLOBAL as bf16 (halves the dominant write stream).
__global__ __launch_bounds__(256) void lstm_fused(
    const ushort* __restrict__ A1h, int Kend1,
    const int*   __restrict__ feat,   // features + t
    const float* __restrict__ G1,
    ushort* __restrict__ c1, ushort* __restrict__ h1out,
    const ushort* __restrict__ A2x, const ushort* __restrict__ A2h, int Kend2,
    const float* __restrict__ b2,
    ushort* __restrict__ c2, ushort* __restrict__ h2out,
    const ushort* __restrict__ W1f, const ushort* __restrict__ W2f) {

    const int z = blockIdx.z;
    const int Kend = z ? Kend2 : Kend1;
    if (Kend < 0) return;
    const int KT = z ? 16 : 8;                 // K/32
    const ushort* __restrict__ Wf = z ? W2f : W1f;

    __shared__ __align__(16) ushort As[2][4096];   // 512 chunks x 16B
    __shared__ __align__(16) ushort Ws[2][4096];

    const int tid = threadIdx.x;
    const int w = tid >> 6, l = tid & 63;
    const int l15 = l & 15, l4 = l >> 4;
    const int m0 = blockIdx.x * 128;
    const int hb = blockIdx.y;                 // h-block
    const int h0 = hb * 32;

    // staging: wave tw stages chunk-blocks S0=tw*2, S1=tw*2+1 (64 chunks each)
    const int rowS0 = w * 32 + l15;            // S0: fg=0
    const int rowS1 = w * 32 + 16 + l15;       // S1: fg=1
    const int kq8 = l4 * 8;
    const int S0 = w * 2, S1 = w * 2 + 1;
    const size_t wtileb = (size_t)hb * KT * 512;   // W fragment base for this h-block

    // fragment read offsets (shorts)
    const int aoff0 = (w * 128 + l) * 8;           // chunk (w*2+0)*64 + l
    const int aoff1 = (w * 128 + 64 + l) * 8;      // chunk (w*2+1)*64 + l
    const int boff  = l * 8;                        // chunk cf*64 + l  (+cf*512)

    f32x4 acc[2][8];
    const f32x4 zero4 = {0.f, 0.f, 0.f, 0.f};
#pragma unroll
    for (int fg = 0; fg < 2; fg++)
#pragma unroll
        for (int cf = 0; cf < 8; cf++) acc[fg][cf] = zero4;

    auto stage = [&](int buf, int kt) {
        const ushort* Asrc; int kl;
        if (!z || kt < 256) { Asrc = z ? A2x : A1h; kl = kt; }
        else                { Asrc = A2h; kl = kt - 256; }
        // A: per-lane pre-swizzled source, linear LDS dest
        glds16(Asrc + (size_t)(m0 + rowS0) * H_SZ + kl + kq8, As[buf] + S0 * 512);
        glds16(Asrc + (size_t)(m0 + rowS1) * H_SZ + kl + kq8, As[buf] + S1 * 512);
        // W: fragment-ordered global, fully linear
        const ushort* wsrc = Wf + (wtileb + (size_t)(kt >> 5) * 512) * 8;
        glds16(wsrc + (S0 * 64 + l) * 8, Ws[buf] + S0 * 512);
        glds16(wsrc + (S1 * 64 + l) * 8, Ws[buf] + S1 * 512);
    };

    if (Kend > 0) {
        stage(0, 0);
        __syncthreads();
        int cur = 0;
        for (int kt = 0; kt < Kend; kt += 32) {
            // 1) ds-load fragments for this tile
            short8 a0 = *(const short8*)(As[cur] + aoff0);
            short8 a1 = *(const short8*)(As[cur] + aoff1);
            short8 bq[8];
#pragma unroll
            for (int cf = 0; cf < 8; cf++)
                bq[cf] = *(const short8*)(Ws[cur] + cf * 512 + boff);

            // 2) issue async prefetch of next tile into other buffer
            if (kt + 32 < Kend) stage(cur ^ 1, kt + 32);

            // 3) MFMA cluster
            __builtin_amdgcn_s_setprio(1);
#pragma unroll
            for (int cf = 0; cf < 8; cf++) {
                acc[0][cf] = __builtin_amdgcn_mfma_f32_16x16x32_bf16(a0, bq[cf], acc[0][cf], 0, 0, 0);
                acc[1][cf] = __builtin_amdgcn_mfma_f32_16x16x32_bf16(a1, bq[cf], acc[1][cf], 0, 0, 0);
            }
            __builtin_amdgcn_s_setprio(0);
            __syncthreads();
            cur ^= 1;
        }
    }

    // fused LSTM cell epilogue. D layout: row=(l>>4)*4+r, col=l&15.
    ushort* __restrict__ cbuf = z ? c2 : c1;
    ushort* __restrict__ hout = z ? h2out : h1out;
    const bool cz = z ? (Kend == 256) : (Kend == 0);

#pragma unroll
    for (int fg = 0; fg < 2; fg++) {
#pragma unroll
        for (int r = 0; r < 4; r++) {
            const int grow = m0 + w * 32 + fg * 16 + l4 * 4 + r;
            const float* gb = z ? b2 : (G1 + (size_t)feat[(size_t)grow * T_SZ] * G4);
#pragma unroll
            for (int h16 = 0; h16 < 2; h16++) {
                const int hcol = h0 + h16 * 16 + l15;
                float gi = acc[fg][0 + h16][r] + gb[hcol];
                float gj = acc[fg][2 + h16][r] + gb[256 + hcol];
                float gf = acc[fg][4 + h16][r] + gb[512 + hcol];
                float go = acc[fg][6 + h16][r] + gb[768 + hcol];
                const size_t ci = (size_t)grow * H_SZ + hcol;
                float cp = cz ? 0.f : bf2f(cbuf[ci]);
                float cn = cp * sigm(gf + 1.f) + sigm(gi) * tanhfast(gj);
                float hn = tanhfast(cn) * sigm(go);
                cbuf[ci] = f2bf(cn);
                hout[ci] = f2bf(hn);
            }
        }
    }
}

// dense+loss via MFMA: wave computes 16 rows x 80 v-cols; shfl softmax.
__global__ __launch_bounds__(256) void dense_loss(const ushort* __restrict__ h2,
                                                  const ushort* __restrict__ WdT,
                                                  const float* __restrict__ bd,
                                                  const int* __restrict__ labels,
                                                  float* __restrict__ out) {
    const int tid = threadIdx.x;
    const int w = tid >> 6, l = tid & 63;
    const int l15 = l & 15, l4 = l >> 4;
    const int m0 = blockIdx.x * 64 + w * 16;

    f32x4 acc[5];
    const f32x4 zero4 = {0.f, 0.f, 0.f, 0.f};
#pragma unroll
    for (int cf = 0; cf < 5; cf++) acc[cf] = zero4;

    for (int kt = 0; kt < 256; kt += 32) {
        short8 a = *(const short8*)(h2 + (size_t)(m0 + l15) * H_SZ + l4 * 8 + kt);
#pragma unroll
        for (int cf = 0; cf < 5; cf++) {
            short8 b = *(const short8*)(WdT + (size_t)(cf * 16 + l15) * H_SZ + l4 * 8 + kt);
            acc[cf] = __builtin_amdgcn_mfma_f32_16x16x32_bf16(a, b, acc[cf], 0, 0, 0);
        }
    }
#pragma unroll
    for (int cf = 0; cf < 5; cf++) {
        float bv = bd[cf * 16 + l15];
#pragma unroll
        for (int r = 0; r < 4; r++) acc[cf][r] += bv;
    }

#pragma unroll
    for (int r = 0; r < 4; r++) {
        const int row = m0 + l4 * 4 + r;
        float mx = acc[0][r];
#pragma unroll
        for (int cf = 1; cf < 5; cf++) mx = fmaxf(mx, acc[cf][r]);
#pragma unroll
        for (int msk = 1; msk < 16; msk <<= 1)
            mx = fmaxf(mx, __shfl_xor(mx, msk, 64));
        float s = 0.f;
#pragma unroll
        for (int cf = 0; cf < 5; cf++) s += __expf(acc[cf][r] - mx);
#pragma unroll
        for (int msk = 1; msk < 16; msk <<= 1)
            s += __shfl_xor(s, msk, 64);
        const int lab = labels[row];
        float pl = 0.f;
#pragma unroll
        for (int cf = 0; cf < 5; cf++)
            pl += (cf * 16 + l15 == lab) ? acc[cf][r] : 0.f;
#pragma unroll
        for (int msk = 1; msk < 16; msk <<= 1)
            pl += __shfl_xor(pl, msk, 64);
        if (l15 == 0)
            atomicAdd(out, (logf(s) + mx - pl) * (1.0f / B_SZ));
    }
}

extern "C" void kernel_launch(void* const* d_in, const int* in_sizes, int n_in,
                              void* d_out, int out_size, void* d_ws, size_t ws_size,
                              hipStream_t stream) {
    const int*   features = (const int*)d_in[0];
    const int*   labels   = (const int*)d_in[1];
    const float* emb      = (const float*)d_in[2];
    const float* W1       = (const float*)d_in[3];
    const float* b1       = (const float*)d_in[4];
    const float* W2       = (const float*)d_in[5];
    const float* b2       = (const float*)d_in[6];
    const float* Wd       = (const float*)d_in[7];
    const float* bd       = (const float*)d_in[8];
    float* out = (float*)d_out;

    char* base = (char*)d_ws;
    float*  G1v = (float*)base;      base += (size_t)V_SZ * G4 * 4;            // 320 KB
    ushort* c1  = (ushort*)base;     base += (size_t)B_SZ * H_SZ * 2;          // 2 MB (bf16)
    ushort* c2  = (ushort*)base;     base += (size_t)B_SZ * H_SZ * 2;          // 2 MB (bf16)
    ushort* h1b[2]; ushort* h2b[2];
    h1b[0] = (ushort*)base;          base += (size_t)B_SZ * H_SZ * 2;
    h1b[1] = (ushort*)base;          base += (size_t)B_SZ * H_SZ * 2;
    h2b[0] = (ushort*)base;          base += (size_t)B_SZ * H_SZ * 2;
    h2b[1] = (ushort*)base;          base += (size_t)B_SZ * H_SZ * 2;
    ushort* W1f = (ushort*)base;     base += (size_t)8 * 8 * 512 * 8 * 2;      // 512 KB
    ushort* W2f = (ushort*)base;     base += (size_t)8 * 16 * 512 * 8 * 2;     // 1 MB
    ushort* WdT = (ushort*)base;     base += (size_t)V_SZ * H_SZ * 2;          // 40 KB

    (void)hipMemsetAsync(d_out, 0, sizeof(float), stream);
    g1_kernel<<<(V_SZ * G4 + 255) / 256, 256, 0, stream>>>(emb, W1, b1, G1v);
    wtransf<<<(8 * 8 * 512 * 8) / 256, 256, 0, stream>>>(W1, E_SZ, 7, 3, W1f);
    wtransf<<<(8 * 16 * 512 * 8) / 256, 256, 0, stream>>>(W2, 0, 15, 4, W2f);
    wdtrans<<<(V_SZ * H_SZ + 255) / 256, 256, 0, stream>>>(Wd, WdT);

    dim3 grid(B_SZ / 128, H_SZ / 32, 2), blk(256);
    for (int t = 0; t <= T_SZ; t++) {
        const int Kend1 = (t < T_SZ) ? (t ? 256 : 0) : -1;
        const int Kend2 = (t >= 1) ? ((t >= 2) ? 512 : 256) : -1;
        lstm_fused<<<grid, blk, 0, stream>>>(
            (t && t < T_SZ) ? h1b[(t - 1) & 1] : nullptr, Kend1,
            features + t, G1v, c1, h1b[t & 1],
            (t >= 1) ? h1b[(t - 1) & 1] : nullptr,
            (t >= 2) ? h2b[(t - 2) & 1] : nullptr, Kend2,
            b2, c2, (t >= 1) ? h2b[(t - 1) & 1] : nullptr,
            W1f, W2f);
    }
    dense_loss<<<B_SZ / 64, 256, 0, stream>>>(h2b[(T_SZ - 1) & 1], WdT, bd, labels, out);
}